// Round 6
// baseline (629.871 us; speedup 1.0000x reference)
//
#include <hip/hip_runtime.h>
#include <cstdint>
#include <cstddef>

#define S_LEN 2048
#define SCALE_F 0.07216878364870323f  // 1/sqrt(192)

typedef __attribute__((ext_vector_type(8))) short short8;
typedef __attribute__((ext_vector_type(4))) float f32x4;
typedef __attribute__((ext_vector_type(16))) float f32x16;
typedef __attribute__((ext_vector_type(4))) unsigned short ushort4v;

__device__ __forceinline__ unsigned short f2bf(float f) {
  unsigned int u = __builtin_bit_cast(unsigned int, f);
  u += 0x7FFFu + ((u >> 16) & 1u);
  return (unsigned short)(u >> 16);
}
__device__ __forceinline__ float bf2f(unsigned short h) {
  unsigned int u = ((unsigned int)h) << 16;
  return __builtin_bit_cast(float, u);
}
__device__ __forceinline__ unsigned int cvt_pk_bf16(float lo, float hi) {
  unsigned int r;
  asm("v_cvt_pk_bf16_f32 %0, %1, %2" : "=v"(r) : "v"(lo), "v"(hi));
  return r;
}

typedef const __attribute__((address_space(1))) void* gas_ptr;
typedef __attribute__((address_space(3))) void* las_ptr;
__device__ __forceinline__ void gload16(const void* g, void* l) {
  __builtin_amdgcn_global_load_lds((gas_ptr)g, (las_ptr)l, 16, 0, 0);
}

// ---------------- fused prep kernel ----------------
// jobs by block range: 7 weight transposes, x cast, rope table, bias concat.

__device__ __forceinline__ void transpose_tile(
    const float* __restrict__ src, unsigned short* __restrict__ dst,
    int K, int N, int kb, int nb) {
  __shared__ __align__(16) unsigned short tile[64][72];
  const int tid = threadIdx.x;
  #pragma unroll
  for (int i = 0; i < 4; ++i) {
    int idx = i * 256 + tid;
    int row = idx >> 4, c4 = (idx & 15) << 2;
    const float4 v = *reinterpret_cast<const float4*>(&src[(size_t)(kb + row) * N + nb + c4]);
    tile[row][c4 + 0] = f2bf(v.x);
    tile[row][c4 + 1] = f2bf(v.y);
    tile[row][c4 + 2] = f2bf(v.z);
    tile[row][c4 + 3] = f2bf(v.w);
  }
  __syncthreads();
  #pragma unroll
  for (int i = 0; i < 4; ++i) {
    int idx = i * 256 + tid;
    int n = idx >> 4, kc = (idx & 15) << 2;
    ushort4v o = { tile[kc + 0][n], tile[kc + 1][n], tile[kc + 2][n], tile[kc + 3][n] };
    *reinterpret_cast<ushort4v*>(&dst[(size_t)(nb + n) * K + kb + kc]) = o;
  }
}

__global__ __launch_bounds__(256) void k_prep(
    const float* __restrict__ x, const float* __restrict__ freq,
    const float* __restrict__ wdq, const float* __restrict__ wdkv,
    const float* __restrict__ wkr, const float* __restrict__ wuq,
    const float* __restrict__ wqr, const float* __restrict__ wukv,
    const float* __restrict__ wo,
    const float* __restrict__ b_uq, const float* __restrict__ b_qr,
    const float* __restrict__ b_dq, const float* __restrict__ b_dkv,
    const float* __restrict__ b_kr,
    unsigned short* __restrict__ x_bf, unsigned short* __restrict__ wd_t,
    unsigned short* __restrict__ wqc_t, unsigned short* __restrict__ wukv_t,
    unsigned short* __restrict__ wo_t, float* __restrict__ tab,
    float* __restrict__ bcat, float* __restrict__ ball) {
  const int bid = blockIdx.x;
  const int tid = threadIdx.x;
  if (bid < 384) {
    transpose_tile(wdq, wd_t, 2048, 768, (bid / 12) << 6, (bid % 12) << 6);
  } else if (bid < 640) {
    int r = bid - 384;
    transpose_tile(wdkv, wd_t + (size_t)768 * 2048, 2048, 512, (r >> 3) << 6, (r & 7) << 6);
  } else if (bid < 672) {
    int r = bid - 640;
    transpose_tile(wkr, wd_t + (size_t)1280 * 2048, 2048, 64, r << 6, 0);
  } else if (bid < 1056) {
    int r = bid - 672;
    transpose_tile(wuq, wqc_t, 768, 2048, (r >> 5) << 6, (r & 31) << 6);
  } else if (bid < 1248) {
    int r = bid - 1056;
    transpose_tile(wqr, wqc_t + (size_t)2048 * 768, 768, 1024, (r >> 4) << 6, (r & 15) << 6);
  } else if (bid < 1760) {
    int r = bid - 1248;
    transpose_tile(wukv, wukv_t, 512, 4096, (r >> 6) << 6, (r & 63) << 6);
  } else if (bid < 2784) {
    int r = bid - 1760;
    transpose_tile(wo, wo_t, 2048, 2048, (r >> 5) << 6, (r & 31) << 6);
  } else if (bid < 10976) {
    int i = (bid - 2784) * 256 + tid;  // 4096*2048/4 = 2097152 float4 groups
    const float4 v = reinterpret_cast<const float4*>(x)[i];
    ushort4v o = { f2bf(v.x), f2bf(v.y), f2bf(v.z), f2bf(v.w) };
    reinterpret_cast<ushort4v*>(x_bf)[i] = o;
  } else if (bid < 11232) {
    int i = (bid - 10976) * 256 + tid;  // 2048*32
    float f = freq[i];
    tab[2 * i] = cosf(f);
    tab[2 * i + 1] = sinf(f);
  } else {
    int i = (bid - 11232) * 256 + tid;
    if (i < 2048) bcat[i] = b_uq[i];
    else if (i < 3072) bcat[i] = b_qr[i - 2048];
    else if (i < 3840) ball[i - 3072] = b_dq[i - 3072];
    else if (i < 4352) ball[i - 3072] = b_dkv[i - 3840];
    else if (i < 4416) ball[i - 3072] = b_kr[i - 4352];
  }
}

__global__ void k_rope_kr(const unsigned short* __restrict__ src, int src_stride,
                          const float* __restrict__ tab,
                          unsigned short* __restrict__ out, int npairs) {
  int idx = blockIdx.x * 256 + threadIdx.x;
  if (idx >= npairs) return;
  int bs = idx >> 5, p = idx & 31;
  int s = bs & (S_LEN - 1);
  float c = tab[(s * 32 + p) * 2], sn = tab[(s * 32 + p) * 2 + 1];
  float x1 = bf2f(src[(size_t)bs * src_stride + 2 * p]);
  float x2 = bf2f(src[(size_t)bs * src_stride + 2 * p + 1]);
  out[bs * 64 + 2 * p] = f2bf(x1 * c - x2 * sn);
  out[bs * 64 + 2 * p + 1] = f2bf(x1 * sn + x2 * c);
}

// ---------------- GEMM (m97 structure): C[M,N] = A[M,K] * Bt[N,K]^T + bias ----------------
template <int OUT_BF16>
__global__ __launch_bounds__(256) void k_gemm_bt(
    const unsigned short* __restrict__ A, const unsigned short* __restrict__ Bt,
    const float* __restrict__ bias, void* __restrict__ Cout, int M, int N, int K,
    int lda, int ldc) {
  __shared__ __align__(16) unsigned short As[128 * 32];
  __shared__ __align__(16) unsigned short Bs[128 * 32];
  const int tid = threadIdx.x;
  const int lane = tid & 63, wid = tid >> 6;
  const int wr = wid >> 1, wc = wid & 1;
  const int m0 = blockIdx.y << 7, n0 = blockIdx.x << 7;
  const int l15 = lane & 15, g = lane >> 4;

  const int srow = (wid << 5) + (lane >> 2);
  const int scol = (lane & 3) << 3;
  const unsigned short* aptr0 = &A[(size_t)(m0 + srow) * lda + scol];
  const unsigned short* aptr1 = &A[(size_t)(m0 + srow + 16) * lda + scol];
  int br0 = n0 + srow;      if (br0 >= N) br0 = N - 1;
  int br1 = n0 + srow + 16; if (br1 >= N) br1 = N - 1;
  const unsigned short* bptr0 = &Bt[(size_t)br0 * K + scol];
  const unsigned short* bptr1 = &Bt[(size_t)br1 * K + scol];
  unsigned short* lA0 = &As[((wid << 1) + 0) << 9];
  unsigned short* lA1 = &As[((wid << 1) + 1) << 9];
  unsigned short* lB0 = &Bs[((wid << 1) + 0) << 9];
  unsigned short* lB1 = &Bs[((wid << 1) + 1) << 9];

  f32x4 acc[4][4];
  #pragma unroll
  for (int m = 0; m < 4; ++m)
    #pragma unroll
    for (int n = 0; n < 4; ++n) acc[m][n] = f32x4{0.f, 0.f, 0.f, 0.f};

  for (int k0 = 0; k0 < K; k0 += 32) {
    gload16(aptr0 + k0, lA0);
    gload16(aptr1 + k0, lA1);
    gload16(bptr0 + k0, lB0);
    gload16(bptr1 + k0, lB1);
    __syncthreads();
    short8 af[4], bfr[4];
    #pragma unroll
    for (int m = 0; m < 4; ++m)
      af[m] = *reinterpret_cast<const short8*>(&As[(((wr << 6) + (m << 4) + l15) << 5) + (g << 3)]);
    #pragma unroll
    for (int n = 0; n < 4; ++n)
      bfr[n] = *reinterpret_cast<const short8*>(&Bs[(((wc << 6) + (n << 4) + l15) << 5) + (g << 3)]);
    __builtin_amdgcn_s_setprio(1);
    #pragma unroll
    for (int m = 0; m < 4; ++m)
      #pragma unroll
      for (int n = 0; n < 4; ++n)
        acc[m][n] = __builtin_amdgcn_mfma_f32_16x16x32_bf16(af[m], bfr[n], acc[m][n], 0, 0, 0);
    __builtin_amdgcn_s_setprio(0);
    __syncthreads();
  }
  #pragma unroll
  for (int n = 0; n < 4; ++n) {
    int col = n0 + (wc << 6) + (n << 4) + l15;
    if (col >= N) continue;
    float bv = bias[col];
    #pragma unroll
    for (int m = 0; m < 4; ++m) {
      int rowb = m0 + (wr << 6) + (m << 4) + (g << 2);
      #pragma unroll
      for (int r = 0; r < 4; ++r) {
        float v = acc[m][n][r] + bv;
        if (OUT_BF16)
          reinterpret_cast<unsigned short*>(Cout)[(size_t)(rowb + r) * ldc + col] = f2bf(v);
        else
          reinterpret_cast<float*>(Cout)[(size_t)(rowb + r) * ldc + col] = v;
      }
    }
  }
}

// ---------------- fused causal flash attention (32x32 MFMA, swapped QK, O^T) ----------------
// grid 512 x 512 threads (8 waves: 4 q-strips x 2 KV-parity groups). One 128-q chunk per
// block; chunk = (bid>>8)? 15-u : u so the two blocks sharing a CU ({bid, bid+256}) carry
// complementary work. Q pre-scaled by SCALE at hoist. 2 blocks/CU co-resident (VGPR<=128).
__global__ __launch_bounds__(512, 4) void k_mla_attn(
    const unsigned short* __restrict__ q_raw, const unsigned short* __restrict__ kv_raw,
    const unsigned short* __restrict__ krro, const float* __restrict__ tab,
    unsigned short* __restrict__ attn_out) {
  __shared__ __align__(16) unsigned char smem[73728];
  unsigned short* KcB = reinterpret_cast<unsigned short*>(smem);            // [4][32][128] 32KB
  unsigned short* VtB = reinterpret_cast<unsigned short*>(smem + 32768);    // [4][128][40] 40KB
  float* Msh = reinterpret_cast<float*>(smem);  // merge: [4 strips][128 v][33] + ml @16896

  const int tid = threadIdx.x;
  const int lane = tid & 63, w = tid >> 6;
  const int s = w & 3, e = w >> 2;
  const int l31 = lane & 31, hi = lane >> 5;
  const int hi8 = hi << 3;
  const int bid = blockIdx.x;
  const int bh = bid & 31, b = bh >> 4, h = bh & 15;
  const int uu = (bid >> 5) & 7;
  const int chunk = (bid >> 8) ? (15 - uu) : uu;
  const size_t bsb = (size_t)b * S_LEN;

  const int vkv = l31;
  const int vg = (w << 1) | hi;
  const int krow0 = (s << 3) + (lane >> 4);
  const int kunit = lane & 15;

  const int q0 = (chunk << 7) + (s << 5);
  const int srow = q0 + l31;
  const int ntb = (chunk << 2) + 4;
  const int U = ntb >> 1;
  const int nt_w = (q0 + 63) >> 5;

  // ---- Q fragments, pre-scaled by SCALE: lane holds Q[d=16ks+8hi+e][q=l31] ----
  short8 qf[12];
  {
    const size_t qrow = (bsb + q0 + l31) * 3072;
    #pragma unroll
    for (int ks = 0; ks < 8; ++ks) {
      short8 rv = *reinterpret_cast<const short8*>(&q_raw[qrow + h * 128 + ks * 16 + hi8]);
      union { unsigned short us[8]; short8 v; } uq;
      #pragma unroll
      for (int j = 0; j < 8; ++j)
        uq.us[j] = f2bf(bf2f((unsigned short)rv[j]) * SCALE_F);
      qf[ks] = uq.v;
    }
    #pragma unroll
    for (int f = 0; f < 4; ++f) {
      short8 rv = *reinterpret_cast<const short8*>(
          &q_raw[qrow + 2048 + h * 64 + f * 16 + hi8]);
      int pi0 = 8 * f + 4 * hi;
      union { unsigned short us[8]; short8 v; } uq;
      #pragma unroll
      for (int j = 0; j < 4; ++j) {
        float c = tab[(srow * 32 + pi0 + j) * 2];
        float sn = tab[(srow * 32 + pi0 + j) * 2 + 1];
        float x1 = bf2f((unsigned short)rv[2 * j]);
        float x2 = bf2f((unsigned short)rv[2 * j + 1]);
        uq.us[2 * j] = f2bf((x1 * c - x2 * sn) * SCALE_F);
        uq.us[2 * j + 1] = f2bf((x1 * sn + x2 * c) * SCALE_F);
      }
      qf[8 + f] = uq.v;
    }
  }

  f32x16 acc[4];
  #pragma unroll
  for (int a = 0; a < 4; ++a)
    #pragma unroll
    for (int r = 0; r < 16; ++r) acc[a][r] = 0.f;
  float mrun = -1e30f, lsum = 0.f;

  // ---- prologue: group e stages Kc tile e; all threads stage V tiles 0,1 ----
  {
    const int ts = e;
    gload16(&kv_raw[(bsb + (ts << 5) + krow0) * 4096 + h * 256 + (kunit ^ (krow0 & 15)) * 8],
            &KcB[(ts << 12) + ((s << 3) << 7)]);
    gload16(&kv_raw[(bsb + (ts << 5) + krow0 + 4) * 4096 + h * 256 + (kunit ^ ((krow0 + 4) & 15)) * 8],
            &KcB[(ts << 12) + (((s << 3) + 4) << 7)]);
    int4 v0 = *reinterpret_cast<const int4*>(&kv_raw[(bsb + vkv) * 4096 + h * 256 + 128 + vg * 8]);
    int4 v1 = *reinterpret_cast<const int4*>(&kv_raw[(bsb + 32 + vkv) * 4096 + h * 256 + 128 + vg * 8]);
    const unsigned short* p0 = reinterpret_cast<const unsigned short*>(&v0);
    const unsigned short* p1 = reinterpret_cast<const unsigned short*>(&v1);
    #pragma unroll
    for (int j = 0; j < 8; ++j) VtB[0 * 5120 + (vg * 8 + j) * 40 + vkv] = p0[j];
    #pragma unroll
    for (int j = 0; j < 8; ++j) VtB[1 * 5120 + (vg * 8 + j) * 40 + vkv] = p1[j];
  }
  __syncthreads();

  for (int u = 0; u < U; ++u) {
    // ---- issue Kc prefetch for tile 2u+2+e ----
    {
      int tsK = (u << 1) + 2 + e;
      if (tsK < ntb) {
        int buf = tsK & 3;
        gload16(&kv_raw[(bsb + (tsK << 5) + krow0) * 4096 + h * 256 + (kunit ^ (krow0 & 15)) * 8],
                &KcB[(buf << 12) + ((s << 3) << 7)]);
        gload16(&kv_raw[(bsb + (tsK << 5) + krow0 + 4) * 4096 + h * 256 + (kunit ^ ((krow0 + 4) & 15)) * 8],
                &KcB[(buf << 12) + (((s << 3) + 4) << 7)]);
      }
    }
    int4 vA, vB;
    const int tA = (u << 1) + 2, tB = (u << 1) + 3;
    const bool doA = tA < ntb, doB = tB < ntb;
    if (doA) vA = *reinterpret_cast<const int4*>(
        &kv_raw[(bsb + (tA << 5) + vkv) * 4096 + h * 256 + 128 + vg * 8]);
    if (doB) vB = *reinterpret_cast<const int4*>(
        &kv_raw[(bsb + (tB << 5) + vkv) * 4096 + h * 256 + 128 + vg * 8]);

    // ---- compute my tile t = 2u+e ----
    const int t = (u << 1) + e;
    if (t < nt_w) {
      const int kvb = t << 5;
      const int kbuf = t & 3;
      short8 krf[4];
      #pragma unroll
      for (int f = 0; f < 4; ++f)
        krf[f] = *reinterpret_cast<const short8*>(
            &krro[(bsb + kvb + l31) * 64 + f * 16 + hi8]);

      f32x16 sca, scb;
      #pragma unroll
      for (int r = 0; r < 16; ++r) { sca[r] = 0.f; scb[r] = 0.f; }
      __builtin_amdgcn_s_setprio(1);
      #pragma unroll
      for (int j = 0; j < 4; ++j) {
        short8 k0 = *reinterpret_cast<const short8*>(
            &KcB[(kbuf << 12) + (l31 << 7) + ((((2 * (2 * j)) | hi) ^ (l31 & 15)) << 3)]);
        sca = __builtin_amdgcn_mfma_f32_32x32x16_bf16(k0, qf[2 * j], sca, 0, 0, 0);
        short8 k1 = *reinterpret_cast<const short8*>(
            &KcB[(kbuf << 12) + (l31 << 7) + ((((2 * (2 * j + 1)) | hi) ^ (l31 & 15)) << 3)]);
        scb = __builtin_amdgcn_mfma_f32_32x32x16_bf16(k1, qf[2 * j + 1], scb, 0, 0, 0);
      }
      sca = __builtin_amdgcn_mfma_f32_32x32x16_bf16(krf[0], qf[8], sca, 0, 0, 0);
      scb = __builtin_amdgcn_mfma_f32_32x32x16_bf16(krf[1], qf[9], scb, 0, 0, 0);
      sca = __builtin_amdgcn_mfma_f32_32x32x16_bf16(krf[2], qf[10], sca, 0, 0, 0);
      scb = __builtin_amdgcn_mfma_f32_32x32x16_bf16(krf[3], qf[11], scb, 0, 0, 0);
      __builtin_amdgcn_s_setprio(0);
      f32x16 sc = sca + scb;

      // causal mask on diagonal tiles only (scores already scaled via Q)
      if (kvb + 31 > q0) {
        #pragma unroll
        for (int r = 0; r < 16; ++r) {
          int kv = kvb + (r & 3) + ((r >> 2) << 3) + (hi << 2);
          if (kv > srow) sc[r] = -1e30f;
        }
      }
      float m0 = fmaxf(fmaxf(sc[0], sc[1]), fmaxf(sc[2], sc[3]));
      float m1 = fmaxf(fmaxf(sc[4], sc[5]), fmaxf(sc[6], sc[7]));
      float m2 = fmaxf(fmaxf(sc[8], sc[9]), fmaxf(sc[10], sc[11]));
      float m3 = fmaxf(fmaxf(sc[12], sc[13]), fmaxf(sc[14], sc[15]));
      float tmax = fmaxf(fmaxf(m0, m1), fmaxf(m2, m3));
      tmax = fmaxf(tmax, __shfl_xor(tmax, 32));

      bool rescale = !__all(tmax <= mrun + 8.f);
      float scold = 1.f;
      if (rescale) {
        float mm = fmaxf(mrun, tmax);
        scold = __expf(mrun - mm);
        mrun = mm;
      }
      float pe[16];
      float ts = 0.f;
      #pragma unroll
      for (int r = 0; r < 16; ++r) { pe[r] = __expf(sc[r] - mrun); ts += pe[r]; }
      ts += __shfl_xor(ts, 32);
      lsum = lsum * scold + ts;

      if (rescale) {
        #pragma unroll
        for (int a = 0; a < 4; ++a)
          #pragma unroll
          for (int r = 0; r < 16; ++r) acc[a][r] *= scold;
      }
      #pragma unroll
      for (int ks = 0; ks < 2; ++ks) {
        unsigned int X0 = cvt_pk_bf16(pe[8 * ks + 0], pe[8 * ks + 1]);
        unsigned int X1 = cvt_pk_bf16(pe[8 * ks + 2], pe[8 * ks + 3]);
        unsigned int Y0 = cvt_pk_bf16(pe[8 * ks + 4], pe[8 * ks + 5]);
        unsigned int Y1 = cvt_pk_bf16(pe[8 * ks + 6], pe[8 * ks + 7]);
        unsigned int send0 = hi ? X0 : Y0;
        unsigned int send1 = hi ? X1 : Y1;
        unsigned int recv0 = (unsigned int)__shfl_xor((int)send0, 32);
        unsigned int recv1 = (unsigned int)__shfl_xor((int)send1, 32);
        union { unsigned int u[4]; short8 v; } pa;
        pa.u[0] = hi ? recv0 : X0;
        pa.u[1] = hi ? recv1 : X1;
        pa.u[2] = hi ? Y0 : recv0;
        pa.u[3] = hi ? Y1 : recv1;
        __builtin_amdgcn_s_setprio(1);
        #pragma unroll
        for (int a = 0; a < 4; ++a) {
          short8 va = *reinterpret_cast<const short8*>(
              &VtB[kbuf * 5120 + (32 * a + l31) * 40 + ks * 16 + hi8]);
          acc[a] = __builtin_amdgcn_mfma_f32_32x32x16_bf16(va, pa.v, acc[a], 0, 0, 0);
        }
        __builtin_amdgcn_s_setprio(0);
      }
    }

    // ---- write prefetched V tiles (issue-early / write-late) ----
    if (doA) {
      const unsigned short* pv = reinterpret_cast<const unsigned short*>(&vA);
      #pragma unroll
      for (int j = 0; j < 8; ++j) VtB[(tA & 3) * 5120 + (vg * 8 + j) * 40 + vkv] = pv[j];
    }
    if (doB) {
      const unsigned short* pv = reinterpret_cast<const unsigned short*>(&vB);
      #pragma unroll
      for (int j = 0; j < 8; ++j) VtB[(tB & 3) * 5120 + (vg * 8 + j) * 40 + vkv] = pv[j];
    }
    __syncthreads();
  }

  // ---- flash merge of parity groups; acc = O^T[v][q=l31], m/l lane-local ----
  if (e == 1) {
    #pragma unroll
    for (int a = 0; a < 4; ++a)
      #pragma unroll
      for (int r = 0; r < 16; ++r) {
        int v = 32 * a + (r & 3) + ((r >> 2) << 3) + (hi << 2);
        Msh[((s << 7) + v) * 33 + l31] = acc[a][r];
      }
    if (hi == 0) {
      Msh[16896 + ((s << 5) + l31) * 2 + 0] = mrun;
      Msh[16896 + ((s << 5) + l31) * 2 + 1] = lsum;
    }
  }
  __syncthreads();
  if (e == 0) {
    float m1 = Msh[16896 + ((s << 5) + l31) * 2 + 0];
    float l1 = Msh[16896 + ((s << 5) + l31) * 2 + 1];
    float mm = fmaxf(mrun, m1);
    float ea = __expf(mrun - mm), eb = __expf(m1 - mm);
    float linv = 1.f / (lsum * ea + l1 * eb);
    float al = ea * linv, be = eb * linv;
    #pragma unroll
    for (int a = 0; a < 4; ++a)
      #pragma unroll
      for (int r = 0; r < 16; ++r) {
        int v = 32 * a + (r & 3) + ((r >> 2) << 3) + (hi << 2);
        float part = Msh[((s << 7) + v) * 33 + l31];
        acc[a][r] = acc[a][r] * al + part * be;
      }
    unsigned int* Tb = reinterpret_cast<unsigned int*>(smem) + s * 4224;
    #pragma unroll
    for (int a = 0; a < 4; ++a)
      #pragma unroll
      for (int j = 0; j < 8; ++j) {
        unsigned int word = cvt_pk_bf16(acc[a][2 * j], acc[a][2 * j + 1]);
        int wc = 16 * a + 2 * hi + (j & 1) + 4 * (j >> 1);
        Tb[l31 * 68 + wc] = word;
      }
    const unsigned char* Tbb = reinterpret_cast<const unsigned char*>(Tb);
    #pragma unroll
    for (int u2 = 0; u2 < 8; ++u2) {
      int qr = (u2 << 2) + (lane >> 4);
      int4 rd = *reinterpret_cast<const int4*>(&Tbb[qr * 272 + (lane & 15) * 16]);
      *reinterpret_cast<int4*>(
          &attn_out[(bsb + q0 + qr) * 2048 + h * 128 + (lane & 15) * 8]) = rd;
    }
  }
}

// ---------------- launch ----------------

extern "C" void kernel_launch(void* const* d_in, const int* in_sizes, int n_in,
                              void* d_out, int out_size, void* d_ws, size_t ws_size,
                              hipStream_t stream) {
  (void)in_sizes; (void)n_in; (void)out_size; (void)ws_size;
  const float* x = (const float*)d_in[0];
  const float* freq = (const float*)d_in[1];
  // d_in[2] = mask: always causal tril -> handled analytically
  const float* w_dq = (const float*)d_in[3];
  const float* b_dq = (const float*)d_in[4];
  const float* w_uq = (const float*)d_in[5];
  const float* b_uq = (const float*)d_in[6];
  const float* w_qr = (const float*)d_in[7];
  const float* b_qr = (const float*)d_in[8];
  const float* w_dkv = (const float*)d_in[9];
  const float* b_dkv = (const float*)d_in[10];
  const float* w_ukv = (const float*)d_in[11];
  const float* b_ukv = (const float*)d_in[12];
  const float* w_kr = (const float*)d_in[13];
  const float* b_kr = (const float*)d_in[14];
  const float* w_o = (const float*)d_in[15];
  const float* b_o = (const float*)d_in[16];

  char* ws = (char*)d_ws;
  size_t off = 0;
  auto alloc = [&](size_t bytes) {
    char* p = ws + off;
    off += (bytes + 255) & ~(size_t)255;
    return p;
  };
  unsigned short* x_bf   = (unsigned short*)alloc((size_t)4096 * 2048 * 2);
  unsigned short* wd_t   = (unsigned short*)alloc((size_t)1344 * 2048 * 2);  // dq|dkv|kr rows
  unsigned short* wqc_t  = (unsigned short*)alloc((size_t)3072 * 768 * 2);
  unsigned short* wukv_t = (unsigned short*)alloc((size_t)4096 * 512 * 2);
  unsigned short* wo_t   = (unsigned short*)alloc((size_t)2048 * 2048 * 2);
  float* tab             = (float*)alloc((size_t)2048 * 32 * 2 * 4);
  float* bcat            = (float*)alloc((size_t)3072 * 4);
  float* ball            = (float*)alloc((size_t)1344 * 4);
  unsigned short* c_all  = (unsigned short*)alloc((size_t)4096 * 1344 * 2);  // c_q|c_kv|kr_raw
  unsigned short* krro   = (unsigned short*)alloc((size_t)4096 * 64 * 2);
  unsigned short* q_raw  = (unsigned short*)alloc((size_t)4096 * 3072 * 2);
  unsigned short* kv_raw = (unsigned short*)alloc((size_t)4096 * 4096 * 2);
  unsigned short* attn   = (unsigned short*)alloc((size_t)4096 * 2048 * 2);

  // single fused prep: 7 transposes + x cast + rope table + bias concat
  k_prep<<<dim3(11250), dim3(256), 0, stream>>>(
      x, freq, w_dq, w_dkv, w_kr, w_uq, w_qr, w_ukv, w_o,
      b_uq, b_qr, b_dq, b_dkv, b_kr,
      x_bf, wd_t, wqc_t, wukv_t, wo_t, tab, bcat, ball);

  // single merged down-projection: x @ [w_dq|w_dkv|w_kr] -> c_all [4096][1344]
  k_gemm_bt<1><<<dim3(11, 32), dim3(256), 0, stream>>>(
      x_bf, wd_t, ball, c_all, 4096, 1344, 2048, 2048, 1344);
  k_rope_kr<<<dim3(512), dim3(256), 0, stream>>>(c_all + 1280, 1344, tab, krro, 4096 * 32);

  // up-projections
  k_gemm_bt<1><<<dim3(24, 32), dim3(256), 0, stream>>>(
      c_all, wqc_t, bcat, q_raw, 4096, 3072, 768, 1344, 3072);
  k_gemm_bt<1><<<dim3(32, 32), dim3(256), 0, stream>>>(
      c_all + 768, wukv_t, b_ukv, kv_raw, 4096, 4096, 512, 1344, 4096);

  // fused causal attention: one chunk per block, complementary co-residency
  k_mla_attn<<<dim3(512), dim3(512), 0, stream>>>(q_raw, kv_raw, krro, tab, attn);

  // output projection -> f32
  k_gemm_bt<0><<<dim3(16, 32), dim3(256), 0, stream>>>(
      attn, wo_t, b_o, (float*)d_out, 4096, 2048, 2048, 2048, 2048);
}

// Round 7
// 292.412 us; speedup vs baseline: 2.1541x; 2.1541x over previous
//
#include <hip/hip_runtime.h>
#include <cstdint>
#include <cstddef>

#define S_LEN 2048
#define SCALE_F 0.07216878364870323f  // 1/sqrt(192)

typedef __attribute__((ext_vector_type(8))) short short8;
typedef __attribute__((ext_vector_type(4))) float f32x4;
typedef __attribute__((ext_vector_type(16))) float f32x16;
typedef __attribute__((ext_vector_type(4))) unsigned short ushort4v;

__device__ __forceinline__ unsigned short f2bf(float f) {
  unsigned int u = __builtin_bit_cast(unsigned int, f);
  u += 0x7FFFu + ((u >> 16) & 1u);
  return (unsigned short)(u >> 16);
}
__device__ __forceinline__ float bf2f(unsigned short h) {
  unsigned int u = ((unsigned int)h) << 16;
  return __builtin_bit_cast(float, u);
}
__device__ __forceinline__ unsigned int cvt_pk_bf16(float lo, float hi) {
  unsigned int r;
  asm("v_cvt_pk_bf16_f32 %0, %1, %2" : "=v"(r) : "v"(lo), "v"(hi));
  return r;
}

typedef const __attribute__((address_space(1))) void* gas_ptr;
typedef __attribute__((address_space(3))) void* las_ptr;
__device__ __forceinline__ void gload16(const void* g, void* l) {
  __builtin_amdgcn_global_load_lds((gas_ptr)g, (las_ptr)l, 16, 0, 0);
}

// ---------------- fused prep kernel ----------------

__device__ __forceinline__ void transpose_tile(
    const float* __restrict__ src, unsigned short* __restrict__ dst,
    int K, int N, int kb, int nb) {
  __shared__ __align__(16) unsigned short tile[64][72];
  const int tid = threadIdx.x;
  #pragma unroll
  for (int i = 0; i < 4; ++i) {
    int idx = i * 256 + tid;
    int row = idx >> 4, c4 = (idx & 15) << 2;
    const float4 v = *reinterpret_cast<const float4*>(&src[(size_t)(kb + row) * N + nb + c4]);
    tile[row][c4 + 0] = f2bf(v.x);
    tile[row][c4 + 1] = f2bf(v.y);
    tile[row][c4 + 2] = f2bf(v.z);
    tile[row][c4 + 3] = f2bf(v.w);
  }
  __syncthreads();
  #pragma unroll
  for (int i = 0; i < 4; ++i) {
    int idx = i * 256 + tid;
    int n = idx >> 4, kc = (idx & 15) << 2;
    ushort4v o = { tile[kc + 0][n], tile[kc + 1][n], tile[kc + 2][n], tile[kc + 3][n] };
    *reinterpret_cast<ushort4v*>(&dst[(size_t)(nb + n) * K + kb + kc]) = o;
  }
}

__global__ __launch_bounds__(256) void k_prep(
    const float* __restrict__ x, const float* __restrict__ freq,
    const float* __restrict__ wdq, const float* __restrict__ wdkv,
    const float* __restrict__ wkr, const float* __restrict__ wuq,
    const float* __restrict__ wqr, const float* __restrict__ wukv,
    const float* __restrict__ wo,
    const float* __restrict__ b_uq, const float* __restrict__ b_qr,
    const float* __restrict__ b_dq, const float* __restrict__ b_dkv,
    const float* __restrict__ b_kr,
    unsigned short* __restrict__ x_bf, unsigned short* __restrict__ wd_t,
    unsigned short* __restrict__ wqc_t, unsigned short* __restrict__ wukv_t,
    unsigned short* __restrict__ wo_t, float* __restrict__ tab,
    float* __restrict__ bcat, float* __restrict__ ball) {
  const int bid = blockIdx.x;
  const int tid = threadIdx.x;
  if (bid < 384) {
    transpose_tile(wdq, wd_t, 2048, 768, (bid / 12) << 6, (bid % 12) << 6);
  } else if (bid < 640) {
    int r = bid - 384;
    transpose_tile(wdkv, wd_t + (size_t)768 * 2048, 2048, 512, (r >> 3) << 6, (r & 7) << 6);
  } else if (bid < 672) {
    int r = bid - 640;
    transpose_tile(wkr, wd_t + (size_t)1280 * 2048, 2048, 64, r << 6, 0);
  } else if (bid < 1056) {
    int r = bid - 672;
    transpose_tile(wuq, wqc_t, 768, 2048, (r >> 5) << 6, (r & 31) << 6);
  } else if (bid < 1248) {
    int r = bid - 1056;
    transpose_tile(wqr, wqc_t + (size_t)2048 * 768, 768, 1024, (r >> 4) << 6, (r & 15) << 6);
  } else if (bid < 1760) {
    int r = bid - 1248;
    transpose_tile(wukv, wukv_t, 512, 4096, (r >> 6) << 6, (r & 63) << 6);
  } else if (bid < 2784) {
    int r = bid - 1760;
    transpose_tile(wo, wo_t, 2048, 2048, (r >> 5) << 6, (r & 31) << 6);
  } else if (bid < 10976) {
    int i = (bid - 2784) * 256 + tid;
    const float4 v = reinterpret_cast<const float4*>(x)[i];
    ushort4v o = { f2bf(v.x), f2bf(v.y), f2bf(v.z), f2bf(v.w) };
    reinterpret_cast<ushort4v*>(x_bf)[i] = o;
  } else if (bid < 11232) {
    int i = (bid - 10976) * 256 + tid;
    float f = freq[i];
    tab[2 * i] = cosf(f);
    tab[2 * i + 1] = sinf(f);
  } else {
    int i = (bid - 11232) * 256 + tid;
    if (i < 2048) bcat[i] = b_uq[i];
    else if (i < 3072) bcat[i] = b_qr[i - 2048];
    else if (i < 3840) ball[i - 3072] = b_dq[i - 3072];
    else if (i < 4352) ball[i - 3072] = b_dkv[i - 3840];
    else if (i < 4416) ball[i - 3072] = b_kr[i - 4352];
  }
}

__global__ void k_rope_kr(const unsigned short* __restrict__ src, int src_stride,
                          const float* __restrict__ tab,
                          unsigned short* __restrict__ out, int npairs) {
  int idx = blockIdx.x * 256 + threadIdx.x;
  if (idx >= npairs) return;
  int bs = idx >> 5, p = idx & 31;
  int s = bs & (S_LEN - 1);
  float c = tab[(s * 32 + p) * 2], sn = tab[(s * 32 + p) * 2 + 1];
  float x1 = bf2f(src[(size_t)bs * src_stride + 2 * p]);
  float x2 = bf2f(src[(size_t)bs * src_stride + 2 * p + 1]);
  out[bs * 64 + 2 * p] = f2bf(x1 * c - x2 * sn);
  out[bs * 64 + 2 * p + 1] = f2bf(x1 * sn + x2 * c);
}

// ---------------- GEMM: C = A * Bt^T + bias; double-buffered 2-phase ----------------
template <int OUT_BF16>
__global__ __launch_bounds__(256) void k_gemm_bt(
    const unsigned short* __restrict__ A, const unsigned short* __restrict__ Bt,
    const float* __restrict__ bias, void* __restrict__ Cout, int M, int N, int K,
    int lda, int ldc) {
  __shared__ __align__(16) unsigned short As[2][128 * 32];
  __shared__ __align__(16) unsigned short Bs[2][128 * 32];
  const int tid = threadIdx.x;
  const int lane = tid & 63, wid = tid >> 6;
  const int wr = wid >> 1, wc = wid & 1;
  const int m0 = blockIdx.y << 7, n0 = blockIdx.x << 7;
  const int l15 = lane & 15, g = lane >> 4;

  const int srow = (wid << 5) + (lane >> 2);
  const int scol = (lane & 3) << 3;
  const unsigned short* aptr0 = &A[(size_t)(m0 + srow) * lda + scol];
  const unsigned short* aptr1 = &A[(size_t)(m0 + srow + 16) * lda + scol];
  int br0 = n0 + srow;      if (br0 >= N) br0 = N - 1;
  int br1 = n0 + srow + 16; if (br1 >= N) br1 = N - 1;
  const unsigned short* bptr0 = &Bt[(size_t)br0 * K + scol];
  const unsigned short* bptr1 = &Bt[(size_t)br1 * K + scol];
  const int lofs0 = ((wid << 1) + 0) << 9;  // wave-uniform 1KB chunk offsets
  const int lofs1 = ((wid << 1) + 1) << 9;

  f32x4 acc[4][4];
  #pragma unroll
  for (int m = 0; m < 4; ++m)
    #pragma unroll
    for (int n = 0; n < 4; ++n) acc[m][n] = f32x4{0.f, 0.f, 0.f, 0.f};

  // prologue: stage K-step 0 into buffer 0
  gload16(aptr0, &As[0][lofs0]);
  gload16(aptr1, &As[0][lofs1]);
  gload16(bptr0, &Bs[0][lofs0]);
  gload16(bptr1, &Bs[0][lofs1]);
  __syncthreads();

  int cur = 0;
  for (int k0 = 0; k0 < K; k0 += 32) {
    const int nxt = cur ^ 1;
    // issue next K-step staging; latency hides under this step's MFMA
    if (k0 + 32 < K) {
      gload16(aptr0 + k0 + 32, &As[nxt][lofs0]);
      gload16(aptr1 + k0 + 32, &As[nxt][lofs1]);
      gload16(bptr0 + k0 + 32, &Bs[nxt][lofs0]);
      gload16(bptr1 + k0 + 32, &Bs[nxt][lofs1]);
    }
    short8 af[4], bfr[4];
    #pragma unroll
    for (int m = 0; m < 4; ++m)
      af[m] = *reinterpret_cast<const short8*>(
          &As[cur][(((wr << 6) + (m << 4) + l15) << 5) + (g << 3)]);
    #pragma unroll
    for (int n = 0; n < 4; ++n)
      bfr[n] = *reinterpret_cast<const short8*>(
          &Bs[cur][(((wc << 6) + (n << 4) + l15) << 5) + (g << 3)]);
    __builtin_amdgcn_s_setprio(1);
    #pragma unroll
    for (int m = 0; m < 4; ++m)
      #pragma unroll
      for (int n = 0; n < 4; ++n)
        acc[m][n] = __builtin_amdgcn_mfma_f32_16x16x32_bf16(af[m], bfr[n], acc[m][n], 0, 0, 0);
    __builtin_amdgcn_s_setprio(0);
    __syncthreads();  // drains next-step staging; protects cur from overwrite
    cur = nxt;
  }
  #pragma unroll
  for (int n = 0; n < 4; ++n) {
    int col = n0 + (wc << 6) + (n << 4) + l15;
    if (col >= N) continue;
    float bv = bias[col];
    #pragma unroll
    for (int m = 0; m < 4; ++m) {
      int rowb = m0 + (wr << 6) + (m << 4) + (g << 2);
      #pragma unroll
      for (int r = 0; r < 4; ++r) {
        float v = acc[m][n][r] + bv;
        if (OUT_BF16)
          reinterpret_cast<unsigned short*>(Cout)[(size_t)(rowb + r) * ldc + col] = f2bf(v);
        else
          reinterpret_cast<float*>(Cout)[(size_t)(rowb + r) * ldc + col] = v;
      }
    }
  }
}

// ---------------- fused causal flash attention (32x32 MFMA, swapped QK, O^T) ----------------
// grid (B*NH, 8), block 512 = 8 waves: 4 q-strips (s, 32 q each) x 2 KV-parity groups (e).
// Block handles chunk pair {c, 15-c} sequentially (uniform work). 1 block/CU, VGPR 128.
// NOTE: do NOT raise launch_bounds waves/EU — acc[4]x16f + qf[12] needs ~128 VGPR;
// forcing 4 waves/EU spills acc to scratch (round-6 regression: 1.3 GB scratch traffic).
__global__ __launch_bounds__(512, 2) void k_mla_attn(
    const unsigned short* __restrict__ q_raw, const unsigned short* __restrict__ kv_raw,
    const unsigned short* __restrict__ krro, const float* __restrict__ tab,
    unsigned short* __restrict__ attn_out) {
  __shared__ __align__(16) unsigned char smem[73728];
  unsigned short* KcB = reinterpret_cast<unsigned short*>(smem);            // [4][32][128] 32KB
  unsigned short* VtB = reinterpret_cast<unsigned short*>(smem + 32768);    // [4][128][40] 40KB
  float* Msh = reinterpret_cast<float*>(smem);  // merge: [4 strips][128 v][33] + ml @16896

  const int tid = threadIdx.x;
  const int lane = tid & 63, w = tid >> 6;
  const int s = w & 3, e = w >> 2;
  const int l31 = lane & 31, hi = lane >> 5;
  const int hi8 = hi << 3;
  const int bh = blockIdx.x, b = bh >> 4, h = bh & 15;
  const size_t bsb = (size_t)b * S_LEN;
  const int p = blockIdx.y;

  const int vkv = l31;
  const int vg = (w << 1) | hi;
  const int krow0 = (s << 3) + (lane >> 4);
  const int kunit = lane & 15;

  for (int half = 0; half < 2; ++half) {
    const int chunk = half ? (15 - p) : p;
    const int q0 = (chunk << 7) + (s << 5);
    const int srow = q0 + l31;
    const int ntb = (chunk << 2) + 4;
    const int U = ntb >> 1;
    const int nt_w = (q0 + 63) >> 5;

    __syncthreads();  // staging vs previous chunk's merge/epilogue

    // ---- Q fragments, pre-scaled by SCALE: lane holds Q[d=16ks+8hi+e][q=l31] ----
    short8 qf[12];
    {
      const size_t qrow = (bsb + q0 + l31) * 3072;
      #pragma unroll
      for (int ks = 0; ks < 8; ++ks) {
        short8 rv = *reinterpret_cast<const short8*>(&q_raw[qrow + h * 128 + ks * 16 + hi8]);
        union { unsigned short us[8]; short8 v; } uq;
        #pragma unroll
        for (int j = 0; j < 8; ++j)
          uq.us[j] = f2bf(bf2f((unsigned short)rv[j]) * SCALE_F);
        qf[ks] = uq.v;
      }
      #pragma unroll
      for (int f = 0; f < 4; ++f) {
        short8 rv = *reinterpret_cast<const short8*>(
            &q_raw[qrow + 2048 + h * 64 + f * 16 + hi8]);
        int pi0 = 8 * f + 4 * hi;
        union { unsigned short us[8]; short8 v; } uq;
        #pragma unroll
        for (int j = 0; j < 4; ++j) {
          float c = tab[(srow * 32 + pi0 + j) * 2];
          float sn = tab[(srow * 32 + pi0 + j) * 2 + 1];
          float x1 = bf2f((unsigned short)rv[2 * j]);
          float x2 = bf2f((unsigned short)rv[2 * j + 1]);
          uq.us[2 * j] = f2bf((x1 * c - x2 * sn) * SCALE_F);
          uq.us[2 * j + 1] = f2bf((x1 * sn + x2 * c) * SCALE_F);
        }
        qf[8 + f] = uq.v;
      }
    }

    f32x16 acc[4];
    #pragma unroll
    for (int a = 0; a < 4; ++a)
      #pragma unroll
      for (int r = 0; r < 16; ++r) acc[a][r] = 0.f;
    float mrun = -1e30f, lsum = 0.f;

    // ---- prologue: group e stages Kc tile e; all threads stage V tiles 0,1 ----
    {
      const int ts = e;
      gload16(&kv_raw[(bsb + (ts << 5) + krow0) * 4096 + h * 256 + (kunit ^ (krow0 & 15)) * 8],
              &KcB[(ts << 12) + ((s << 3) << 7)]);
      gload16(&kv_raw[(bsb + (ts << 5) + krow0 + 4) * 4096 + h * 256 + (kunit ^ ((krow0 + 4) & 15)) * 8],
              &KcB[(ts << 12) + (((s << 3) + 4) << 7)]);
      int4 v0 = *reinterpret_cast<const int4*>(&kv_raw[(bsb + vkv) * 4096 + h * 256 + 128 + vg * 8]);
      int4 v1 = *reinterpret_cast<const int4*>(&kv_raw[(bsb + 32 + vkv) * 4096 + h * 256 + 128 + vg * 8]);
      const unsigned short* p0 = reinterpret_cast<const unsigned short*>(&v0);
      const unsigned short* p1 = reinterpret_cast<const unsigned short*>(&v1);
      #pragma unroll
      for (int j = 0; j < 8; ++j) VtB[0 * 5120 + (vg * 8 + j) * 40 + vkv] = p0[j];
      #pragma unroll
      for (int j = 0; j < 8; ++j) VtB[1 * 5120 + (vg * 8 + j) * 40 + vkv] = p1[j];
    }
    __syncthreads();

    for (int u = 0; u < U; ++u) {
      {
        int tsK = (u << 1) + 2 + e;
        if (tsK < ntb) {
          int buf = tsK & 3;
          gload16(&kv_raw[(bsb + (tsK << 5) + krow0) * 4096 + h * 256 + (kunit ^ (krow0 & 15)) * 8],
                  &KcB[(buf << 12) + ((s << 3) << 7)]);
          gload16(&kv_raw[(bsb + (tsK << 5) + krow0 + 4) * 4096 + h * 256 + (kunit ^ ((krow0 + 4) & 15)) * 8],
                  &KcB[(buf << 12) + (((s << 3) + 4) << 7)]);
        }
      }
      int4 vA, vB;
      const int tA = (u << 1) + 2, tB = (u << 1) + 3;
      const bool doA = tA < ntb, doB = tB < ntb;
      if (doA) vA = *reinterpret_cast<const int4*>(
          &kv_raw[(bsb + (tA << 5) + vkv) * 4096 + h * 256 + 128 + vg * 8]);
      if (doB) vB = *reinterpret_cast<const int4*>(
          &kv_raw[(bsb + (tB << 5) + vkv) * 4096 + h * 256 + 128 + vg * 8]);

      const int t = (u << 1) + e;
      if (t < nt_w) {
        const int kvb = t << 5;
        const int kbuf = t & 3;
        short8 krf[4];
        #pragma unroll
        for (int f = 0; f < 4; ++f)
          krf[f] = *reinterpret_cast<const short8*>(
              &krro[(bsb + kvb + l31) * 64 + f * 16 + hi8]);

        f32x16 sca, scb;
        #pragma unroll
        for (int r = 0; r < 16; ++r) { sca[r] = 0.f; scb[r] = 0.f; }
        __builtin_amdgcn_s_setprio(1);
        #pragma unroll
        for (int j = 0; j < 4; ++j) {
          short8 k0 = *reinterpret_cast<const short8*>(
              &KcB[(kbuf << 12) + (l31 << 7) + ((((2 * (2 * j)) | hi) ^ (l31 & 15)) << 3)]);
          sca = __builtin_amdgcn_mfma_f32_32x32x16_bf16(k0, qf[2 * j], sca, 0, 0, 0);
          short8 k1 = *reinterpret_cast<const short8*>(
              &KcB[(kbuf << 12) + (l31 << 7) + ((((2 * (2 * j + 1)) | hi) ^ (l31 & 15)) << 3)]);
          scb = __builtin_amdgcn_mfma_f32_32x32x16_bf16(k1, qf[2 * j + 1], scb, 0, 0, 0);
        }
        sca = __builtin_amdgcn_mfma_f32_32x32x16_bf16(krf[0], qf[8], sca, 0, 0, 0);
        scb = __builtin_amdgcn_mfma_f32_32x32x16_bf16(krf[1], qf[9], scb, 0, 0, 0);
        sca = __builtin_amdgcn_mfma_f32_32x32x16_bf16(krf[2], qf[10], sca, 0, 0, 0);
        scb = __builtin_amdgcn_mfma_f32_32x32x16_bf16(krf[3], qf[11], scb, 0, 0, 0);
        __builtin_amdgcn_s_setprio(0);
        f32x16 sc = sca + scb;

        if (kvb + 31 > q0) {
          #pragma unroll
          for (int r = 0; r < 16; ++r) {
            int kv = kvb + (r & 3) + ((r >> 2) << 3) + (hi << 2);
            if (kv > srow) sc[r] = -1e30f;
          }
        }
        float m0 = fmaxf(fmaxf(sc[0], sc[1]), fmaxf(sc[2], sc[3]));
        float m1 = fmaxf(fmaxf(sc[4], sc[5]), fmaxf(sc[6], sc[7]));
        float m2 = fmaxf(fmaxf(sc[8], sc[9]), fmaxf(sc[10], sc[11]));
        float m3 = fmaxf(fmaxf(sc[12], sc[13]), fmaxf(sc[14], sc[15]));
        float tmax = fmaxf(fmaxf(m0, m1), fmaxf(m2, m3));
        tmax = fmaxf(tmax, __shfl_xor(tmax, 32));

        bool rescale = !__all(tmax <= mrun + 8.f);
        float scold = 1.f;
        if (rescale) {
          float mm = fmaxf(mrun, tmax);
          scold = __expf(mrun - mm);
          mrun = mm;
        }
        float pe[16];
        float ts = 0.f;
        #pragma unroll
        for (int r = 0; r < 16; ++r) { pe[r] = __expf(sc[r] - mrun); ts += pe[r]; }
        ts += __shfl_xor(ts, 32);
        lsum = lsum * scold + ts;

        if (rescale) {
          #pragma unroll
          for (int a = 0; a < 4; ++a)
            #pragma unroll
            for (int r = 0; r < 16; ++r) acc[a][r] *= scold;
        }
        #pragma unroll
        for (int ks = 0; ks < 2; ++ks) {
          unsigned int X0 = cvt_pk_bf16(pe[8 * ks + 0], pe[8 * ks + 1]);
          unsigned int X1 = cvt_pk_bf16(pe[8 * ks + 2], pe[8 * ks + 3]);
          unsigned int Y0 = cvt_pk_bf16(pe[8 * ks + 4], pe[8 * ks + 5]);
          unsigned int Y1 = cvt_pk_bf16(pe[8 * ks + 6], pe[8 * ks + 7]);
          unsigned int send0 = hi ? X0 : Y0;
          unsigned int send1 = hi ? X1 : Y1;
          unsigned int recv0 = (unsigned int)__shfl_xor((int)send0, 32);
          unsigned int recv1 = (unsigned int)__shfl_xor((int)send1, 32);
          union { unsigned int u[4]; short8 v; } pa;
          pa.u[0] = hi ? recv0 : X0;
          pa.u[1] = hi ? recv1 : X1;
          pa.u[2] = hi ? Y0 : recv0;
          pa.u[3] = hi ? Y1 : recv1;
          __builtin_amdgcn_s_setprio(1);
          #pragma unroll
          for (int a = 0; a < 4; ++a) {
            short8 va = *reinterpret_cast<const short8*>(
                &VtB[kbuf * 5120 + (32 * a + l31) * 40 + ks * 16 + hi8]);
            acc[a] = __builtin_amdgcn_mfma_f32_32x32x16_bf16(va, pa.v, acc[a], 0, 0, 0);
          }
          __builtin_amdgcn_s_setprio(0);
        }
      }

      if (doA) {
        const unsigned short* pv = reinterpret_cast<const unsigned short*>(&vA);
        #pragma unroll
        for (int j = 0; j < 8; ++j) VtB[(tA & 3) * 5120 + (vg * 8 + j) * 40 + vkv] = pv[j];
      }
      if (doB) {
        const unsigned short* pv = reinterpret_cast<const unsigned short*>(&vB);
        #pragma unroll
        for (int j = 0; j < 8; ++j) VtB[(tB & 3) * 5120 + (vg * 8 + j) * 40 + vkv] = pv[j];
      }
      __syncthreads();
    }

    // ---- flash merge of parity groups; acc = O^T[v][q=l31], m/l lane-local ----
    if (e == 1) {
      #pragma unroll
      for (int a = 0; a < 4; ++a)
        #pragma unroll
        for (int r = 0; r < 16; ++r) {
          int v = 32 * a + (r & 3) + ((r >> 2) << 3) + (hi << 2);
          Msh[((s << 7) + v) * 33 + l31] = acc[a][r];
        }
      if (hi == 0) {
        Msh[16896 + ((s << 5) + l31) * 2 + 0] = mrun;
        Msh[16896 + ((s << 5) + l31) * 2 + 1] = lsum;
      }
    }
    __syncthreads();
    if (e == 0) {
      float m1 = Msh[16896 + ((s << 5) + l31) * 2 + 0];
      float l1 = Msh[16896 + ((s << 5) + l31) * 2 + 1];
      float mm = fmaxf(mrun, m1);
      float ea = __expf(mrun - mm), eb = __expf(m1 - mm);
      float linv = 1.f / (lsum * ea + l1 * eb);
      float al = ea * linv, be = eb * linv;
      #pragma unroll
      for (int a = 0; a < 4; ++a)
        #pragma unroll
        for (int r = 0; r < 16; ++r) {
          int v = 32 * a + (r & 3) + ((r >> 2) << 3) + (hi << 2);
          float part = Msh[((s << 7) + v) * 33 + l31];
          acc[a][r] = acc[a][r] * al + part * be;
        }
      unsigned int* Tb = reinterpret_cast<unsigned int*>(smem) + s * 4224;
      #pragma unroll
      for (int a = 0; a < 4; ++a)
        #pragma unroll
        for (int j = 0; j < 8; ++j) {
          unsigned int word = cvt_pk_bf16(acc[a][2 * j], acc[a][2 * j + 1]);
          int wc = 16 * a + 2 * hi + (j & 1) + 4 * (j >> 1);
          Tb[l31 * 68 + wc] = word;
        }
      const unsigned char* Tbb = reinterpret_cast<const unsigned char*>(Tb);
      #pragma unroll
      for (int u2 = 0; u2 < 8; ++u2) {
        int qr = (u2 << 2) + (lane >> 4);
        int4 rd = *reinterpret_cast<const int4*>(&Tbb[qr * 272 + (lane & 15) * 16]);
        *reinterpret_cast<int4*>(
            &attn_out[(bsb + q0 + qr) * 2048 + h * 128 + (lane & 15) * 8]) = rd;
      }
    }
  }
}

// ---------------- launch ----------------

extern "C" void kernel_launch(void* const* d_in, const int* in_sizes, int n_in,
                              void* d_out, int out_size, void* d_ws, size_t ws_size,
                              hipStream_t stream) {
  (void)in_sizes; (void)n_in; (void)out_size; (void)ws_size;
  const float* x = (const float*)d_in[0];
  const float* freq = (const float*)d_in[1];
  // d_in[2] = mask: always causal tril -> handled analytically
  const float* w_dq = (const float*)d_in[3];
  const float* b_dq = (const float*)d_in[4];
  const float* w_uq = (const float*)d_in[5];
  const float* b_uq = (const float*)d_in[6];
  const float* w_qr = (const float*)d_in[7];
  const float* b_qr = (const float*)d_in[8];
  const float* w_dkv = (const float*)d_in[9];
  const float* b_dkv = (const float*)d_in[10];
  const float* w_ukv = (const float*)d_in[11];
  const float* b_ukv = (const float*)d_in[12];
  const float* w_kr = (const float*)d_in[13];
  const float* b_kr = (const float*)d_in[14];
  const float* w_o = (const float*)d_in[15];
  const float* b_o = (const float*)d_in[16];

  char* ws = (char*)d_ws;
  size_t off = 0;
  auto alloc = [&](size_t bytes) {
    char* p = ws + off;
    off += (bytes + 255) & ~(size_t)255;
    return p;
  };
  unsigned short* x_bf   = (unsigned short*)alloc((size_t)4096 * 2048 * 2);
  unsigned short* wd_t   = (unsigned short*)alloc((size_t)1344 * 2048 * 2);  // dq|dkv|kr rows
  unsigned short* wqc_t  = (unsigned short*)alloc((size_t)3072 * 768 * 2);
  unsigned short* wukv_t = (unsigned short*)alloc((size_t)4096 * 512 * 2);
  unsigned short* wo_t   = (unsigned short*)alloc((size_t)2048 * 2048 * 2);
  float* tab             = (float*)alloc((size_t)2048 * 32 * 2 * 4);
  float* bcat            = (float*)alloc((size_t)3072 * 4);
  float* ball            = (float*)alloc((size_t)1344 * 4);
  unsigned short* c_all  = (unsigned short*)alloc((size_t)4096 * 1344 * 2);  // c_q|c_kv|kr_raw
  unsigned short* krro   = (unsigned short*)alloc((size_t)4096 * 64 * 2);
  unsigned short* q_raw  = (unsigned short*)alloc((size_t)4096 * 3072 * 2);
  unsigned short* kv_raw = (unsigned short*)alloc((size_t)4096 * 4096 * 2);
  unsigned short* attn   = (unsigned short*)alloc((size_t)4096 * 2048 * 2);

  // single fused prep: 7 transposes + x cast + rope table + bias concat
  k_prep<<<dim3(11250), dim3(256), 0, stream>>>(
      x, freq, w_dq, w_dkv, w_kr, w_uq, w_qr, w_ukv, w_o,
      b_uq, b_qr, b_dq, b_dkv, b_kr,
      x_bf, wd_t, wqc_t, wukv_t, wo_t, tab, bcat, ball);

  // single merged down-projection: x @ [w_dq|w_dkv|w_kr] -> c_all [4096][1344]
  k_gemm_bt<1><<<dim3(11, 32), dim3(256), 0, stream>>>(
      x_bf, wd_t, ball, c_all, 4096, 1344, 2048, 2048, 1344);
  k_rope_kr<<<dim3(512), dim3(256), 0, stream>>>(c_all + 1280, 1344, tab, krro, 4096 * 32);

  // up-projections
  k_gemm_bt<1><<<dim3(24, 32), dim3(256), 0, stream>>>(
      c_all, wqc_t, bcat, q_raw, 4096, 3072, 768, 1344, 3072);
  k_gemm_bt<1><<<dim3(32, 32), dim3(256), 0, stream>>>(
      c_all + 768, wukv_t, b_ukv, kv_raw, 4096, 4096, 512, 1344, 4096);

  // fused causal attention: round-5 config (1 block/CU, chunk pairs)
  k_mla_attn<<<dim3(32, 8), dim3(512), 0, stream>>>(q_raw, kv_raw, krro, tab, attn);

  // output projection -> f32
  k_gemm_bt<0><<<dim3(16, 32), dim3(256), 0, stream>>>(
      attn, wo_t, b_o, (float*)d_out, 4096, 2048, 2048, 2048, 2048);
}

// Round 8
// 288.016 us; speedup vs baseline: 2.1869x; 1.0153x over previous
//
#include <hip/hip_runtime.h>
#include <cstdint>
#include <cstddef>

#define S_LEN 2048
#define SCALE_F 0.07216878364870323f  // 1/sqrt(192)

typedef __attribute__((ext_vector_type(8))) short short8;
typedef __attribute__((ext_vector_type(4))) float f32x4;
typedef __attribute__((ext_vector_type(16))) float f32x16;
typedef __attribute__((ext_vector_type(4))) unsigned short ushort4v;

__device__ __forceinline__ unsigned short f2bf(float f) {
  unsigned int u = __builtin_bit_cast(unsigned int, f);
  u += 0x7FFFu + ((u >> 16) & 1u);
  return (unsigned short)(u >> 16);
}
__device__ __forceinline__ float bf2f(unsigned short h) {
  unsigned int u = ((unsigned int)h) << 16;
  return __builtin_bit_cast(float, u);
}
__device__ __forceinline__ unsigned int cvt_pk_bf16(float lo, float hi) {
  unsigned int r;
  asm("v_cvt_pk_bf16_f32 %0, %1, %2" : "=v"(r) : "v"(lo), "v"(hi));
  return r;
}

typedef const __attribute__((address_space(1))) void* gas_ptr;
typedef __attribute__((address_space(3))) void* las_ptr;
__device__ __forceinline__ void gload16(const void* g, void* l) {
  __builtin_amdgcn_global_load_lds((gas_ptr)g, (las_ptr)l, 16, 0, 0);
}

// ---------------- fused prep kernel ----------------

__device__ __forceinline__ void transpose_tile(
    const float* __restrict__ src, unsigned short* __restrict__ dst,
    int K, int N, int kb, int nb) {
  __shared__ __align__(16) unsigned short tile[64][72];
  const int tid = threadIdx.x;
  #pragma unroll
  for (int i = 0; i < 4; ++i) {
    int idx = i * 256 + tid;
    int row = idx >> 4, c4 = (idx & 15) << 2;
    const float4 v = *reinterpret_cast<const float4*>(&src[(size_t)(kb + row) * N + nb + c4]);
    tile[row][c4 + 0] = f2bf(v.x);
    tile[row][c4 + 1] = f2bf(v.y);
    tile[row][c4 + 2] = f2bf(v.z);
    tile[row][c4 + 3] = f2bf(v.w);
  }
  __syncthreads();
  #pragma unroll
  for (int i = 0; i < 4; ++i) {
    int idx = i * 256 + tid;
    int n = idx >> 4, kc = (idx & 15) << 2;
    ushort4v o = { tile[kc + 0][n], tile[kc + 1][n], tile[kc + 2][n], tile[kc + 3][n] };
    *reinterpret_cast<ushort4v*>(&dst[(size_t)(nb + n) * K + kb + kc]) = o;
  }
}

__global__ __launch_bounds__(256) void k_prep(
    const float* __restrict__ x, const float* __restrict__ freq,
    const float* __restrict__ wdq, const float* __restrict__ wdkv,
    const float* __restrict__ wkr, const float* __restrict__ wuq,
    const float* __restrict__ wqr, const float* __restrict__ wukv,
    const float* __restrict__ wo,
    const float* __restrict__ b_uq, const float* __restrict__ b_qr,
    const float* __restrict__ b_dq, const float* __restrict__ b_dkv,
    const float* __restrict__ b_kr,
    unsigned short* __restrict__ x_bf, unsigned short* __restrict__ wd_t,
    unsigned short* __restrict__ wqc_t, unsigned short* __restrict__ wukv_t,
    unsigned short* __restrict__ wo_t, float* __restrict__ tab,
    float* __restrict__ bcat, float* __restrict__ ball) {
  const int bid = blockIdx.x;
  const int tid = threadIdx.x;
  if (bid < 384) {
    transpose_tile(wdq, wd_t, 2048, 768, (bid / 12) << 6, (bid % 12) << 6);
  } else if (bid < 640) {
    int r = bid - 384;
    transpose_tile(wdkv, wd_t + (size_t)768 * 2048, 2048, 512, (r >> 3) << 6, (r & 7) << 6);
  } else if (bid < 672) {
    int r = bid - 640;
    transpose_tile(wkr, wd_t + (size_t)1280 * 2048, 2048, 64, r << 6, 0);
  } else if (bid < 1056) {
    int r = bid - 672;
    transpose_tile(wuq, wqc_t, 768, 2048, (r >> 5) << 6, (r & 31) << 6);
  } else if (bid < 1248) {
    int r = bid - 1056;
    transpose_tile(wqr, wqc_t + (size_t)2048 * 768, 768, 1024, (r >> 4) << 6, (r & 15) << 6);
  } else if (bid < 1760) {
    int r = bid - 1248;
    transpose_tile(wukv, wukv_t, 512, 4096, (r >> 6) << 6, (r & 63) << 6);
  } else if (bid < 2784) {
    int r = bid - 1760;
    transpose_tile(wo, wo_t, 2048, 2048, (r >> 5) << 6, (r & 31) << 6);
  } else if (bid < 10976) {
    int i = (bid - 2784) * 256 + tid;
    const float4 v = reinterpret_cast<const float4*>(x)[i];
    ushort4v o = { f2bf(v.x), f2bf(v.y), f2bf(v.z), f2bf(v.w) };
    reinterpret_cast<ushort4v*>(x_bf)[i] = o;
  } else if (bid < 11232) {
    int i = (bid - 10976) * 256 + tid;
    float f = freq[i];
    tab[2 * i] = cosf(f);
    tab[2 * i + 1] = sinf(f);
  } else {
    int i = (bid - 11232) * 256 + tid;
    if (i < 2048) bcat[i] = b_uq[i];
    else if (i < 3072) bcat[i] = b_qr[i - 2048];
    else if (i < 3840) ball[i - 3072] = b_dq[i - 3072];
    else if (i < 4352) ball[i - 3072] = b_dkv[i - 3840];
    else if (i < 4416) ball[i - 3072] = b_kr[i - 4352];
  }
}

__global__ void k_rope_kr(const unsigned short* __restrict__ src, int src_stride,
                          const float* __restrict__ tab,
                          unsigned short* __restrict__ out, int npairs) {
  int idx = blockIdx.x * 256 + threadIdx.x;
  if (idx >= npairs) return;
  int bs = idx >> 5, p = idx & 31;
  int s = bs & (S_LEN - 1);
  float c = tab[(s * 32 + p) * 2], sn = tab[(s * 32 + p) * 2 + 1];
  float x1 = bf2f(src[(size_t)bs * src_stride + 2 * p]);
  float x2 = bf2f(src[(size_t)bs * src_stride + 2 * p + 1]);
  out[bs * 64 + 2 * p] = f2bf(x1 * c - x2 * sn);
  out[bs * 64 + 2 * p + 1] = f2bf(x1 * sn + x2 * c);
}

// ---------------- GEMM: C = A * Bt^T + bias; double-buffered, XCD-chunked swizzle ----------------
template <int OUT_BF16>
__global__ __launch_bounds__(256) void k_gemm_bt(
    const unsigned short* __restrict__ A, const unsigned short* __restrict__ Bt,
    const float* __restrict__ bias, void* __restrict__ Cout, int M, int N, int K,
    int lda, int ldc) {
  __shared__ __align__(16) unsigned short As[2][128 * 32];
  __shared__ __align__(16) unsigned short Bs[2][128 * 32];
  const int tid = threadIdx.x;
  const int lane = tid & 63, wid = tid >> 6;
  const int wr = wid >> 1, wc = wid & 1;
  // XCD-chunked remap (all launches have nwg % 8 == 0): blocks sharing an
  // A M-panel (same by) land on the same XCD's L2.
  const int nwg = gridDim.x * gridDim.y;
  const int id = blockIdx.y * gridDim.x + blockIdx.x;
  const int l = (id & 7) * (nwg >> 3) + (id >> 3);
  const int m0 = (l / gridDim.x) << 7, n0 = (l % gridDim.x) << 7;
  const int l15 = lane & 15, g = lane >> 4;

  const int srow = (wid << 5) + (lane >> 2);
  const int scol = (lane & 3) << 3;
  const unsigned short* aptr0 = &A[(size_t)(m0 + srow) * lda + scol];
  const unsigned short* aptr1 = &A[(size_t)(m0 + srow + 16) * lda + scol];
  int br0 = n0 + srow;      if (br0 >= N) br0 = N - 1;
  int br1 = n0 + srow + 16; if (br1 >= N) br1 = N - 1;
  const unsigned short* bptr0 = &Bt[(size_t)br0 * K + scol];
  const unsigned short* bptr1 = &Bt[(size_t)br1 * K + scol];
  const int lofs0 = ((wid << 1) + 0) << 9;
  const int lofs1 = ((wid << 1) + 1) << 9;

  f32x4 acc[4][4];
  #pragma unroll
  for (int m = 0; m < 4; ++m)
    #pragma unroll
    for (int n = 0; n < 4; ++n) acc[m][n] = f32x4{0.f, 0.f, 0.f, 0.f};

  gload16(aptr0, &As[0][lofs0]);
  gload16(aptr1, &As[0][lofs1]);
  gload16(bptr0, &Bs[0][lofs0]);
  gload16(bptr1, &Bs[0][lofs1]);
  __syncthreads();

  int cur = 0;
  for (int k0 = 0; k0 < K; k0 += 32) {
    const int nxt = cur ^ 1;
    if (k0 + 32 < K) {
      gload16(aptr0 + k0 + 32, &As[nxt][lofs0]);
      gload16(aptr1 + k0 + 32, &As[nxt][lofs1]);
      gload16(bptr0 + k0 + 32, &Bs[nxt][lofs0]);
      gload16(bptr1 + k0 + 32, &Bs[nxt][lofs1]);
    }
    short8 af[4], bfr[4];
    #pragma unroll
    for (int m = 0; m < 4; ++m)
      af[m] = *reinterpret_cast<const short8*>(
          &As[cur][(((wr << 6) + (m << 4) + l15) << 5) + (g << 3)]);
    #pragma unroll
    for (int n = 0; n < 4; ++n)
      bfr[n] = *reinterpret_cast<const short8*>(
          &Bs[cur][(((wc << 6) + (n << 4) + l15) << 5) + (g << 3)]);
    __builtin_amdgcn_s_setprio(1);
    #pragma unroll
    for (int m = 0; m < 4; ++m)
      #pragma unroll
      for (int n = 0; n < 4; ++n)
        acc[m][n] = __builtin_amdgcn_mfma_f32_16x16x32_bf16(af[m], bfr[n], acc[m][n], 0, 0, 0);
    __builtin_amdgcn_s_setprio(0);
    __syncthreads();
    cur = nxt;
  }
  #pragma unroll
  for (int n = 0; n < 4; ++n) {
    int col = n0 + (wc << 6) + (n << 4) + l15;
    if (col >= N) continue;
    float bv = bias[col];
    #pragma unroll
    for (int m = 0; m < 4; ++m) {
      int rowb = m0 + (wr << 6) + (m << 4) + (g << 2);
      #pragma unroll
      for (int r = 0; r < 4; ++r) {
        float v = acc[m][n][r] + bv;
        if (OUT_BF16)
          reinterpret_cast<unsigned short*>(Cout)[(size_t)(rowb + r) * ldc + col] = f2bf(v);
        else
          reinterpret_cast<float*>(Cout)[(size_t)(rowb + r) * ldc + col] = v;
      }
    }
  }
}

// ---------------- fused causal flash attention (32x32 MFMA, swapped QK, O^T) ----------------
// grid 512, block 512 = 8 waves: 4 q-strips (s, 32 q each) x 2 KV-parity groups (e).
// One 128-q chunk per block; chunk = (bid>>8) ? 15-u : u so the two blocks landing on a
// CU ({i, i+256} under round-robin dispatch) carry complementary work.
// NOTE: keep __launch_bounds__(512, 2): compiles to VGPR=128, which lets TWO blocks
// co-reside per CU (16 waves x 128 VGPR = full file; LDS 2x72KB <= 160KB).
// Do NOT use (512,4): it forces VGPR=64 and spills acc to scratch (round-6: 2x slower).
__global__ __launch_bounds__(512, 2) void k_mla_attn(
    const unsigned short* __restrict__ q_raw, const unsigned short* __restrict__ kv_raw,
    const unsigned short* __restrict__ krro, const float* __restrict__ tab,
    unsigned short* __restrict__ attn_out) {
  __shared__ __align__(16) unsigned char smem[73728];
  unsigned short* KcB = reinterpret_cast<unsigned short*>(smem);            // [4][32][128] 32KB
  unsigned short* VtB = reinterpret_cast<unsigned short*>(smem + 32768);    // [4][128][40] 40KB
  float* Msh = reinterpret_cast<float*>(smem);  // merge: [4 strips][128 v][33] + ml @16896

  const int tid = threadIdx.x;
  const int lane = tid & 63, w = tid >> 6;
  const int s = w & 3, e = w >> 2;
  const int l31 = lane & 31, hi = lane >> 5;
  const int hi8 = hi << 3;
  const int bid = blockIdx.x;
  const int bh = bid & 31, b = bh >> 4, h = bh & 15;
  const int uu = (bid >> 5) & 7;
  const int chunk = (bid >> 8) ? (15 - uu) : uu;
  const size_t bsb = (size_t)b * S_LEN;

  const int vkv = l31;
  const int vg = (w << 1) | hi;
  const int krow0 = (s << 3) + (lane >> 4);
  const int kunit = lane & 15;

  const int q0 = (chunk << 7) + (s << 5);
  const int srow = q0 + l31;
  const int ntb = (chunk << 2) + 4;
  const int U = ntb >> 1;
  const int nt_w = (q0 + 63) >> 5;

  // ---- Q fragments, pre-scaled by SCALE: lane holds Q[d=16ks+8hi+e][q=l31] ----
  short8 qf[12];
  {
    const size_t qrow = (bsb + q0 + l31) * 3072;
    #pragma unroll
    for (int ks = 0; ks < 8; ++ks) {
      short8 rv = *reinterpret_cast<const short8*>(&q_raw[qrow + h * 128 + ks * 16 + hi8]);
      union { unsigned short us[8]; short8 v; } uq;
      #pragma unroll
      for (int j = 0; j < 8; ++j)
        uq.us[j] = f2bf(bf2f((unsigned short)rv[j]) * SCALE_F);
      qf[ks] = uq.v;
    }
    #pragma unroll
    for (int f = 0; f < 4; ++f) {
      short8 rv = *reinterpret_cast<const short8*>(
          &q_raw[qrow + 2048 + h * 64 + f * 16 + hi8]);
      int pi0 = 8 * f + 4 * hi;
      union { unsigned short us[8]; short8 v; } uq;
      #pragma unroll
      for (int j = 0; j < 4; ++j) {
        float c = tab[(srow * 32 + pi0 + j) * 2];
        float sn = tab[(srow * 32 + pi0 + j) * 2 + 1];
        float x1 = bf2f((unsigned short)rv[2 * j]);
        float x2 = bf2f((unsigned short)rv[2 * j + 1]);
        uq.us[2 * j] = f2bf((x1 * c - x2 * sn) * SCALE_F);
        uq.us[2 * j + 1] = f2bf((x1 * sn + x2 * c) * SCALE_F);
      }
      qf[8 + f] = uq.v;
    }
  }

  f32x16 acc[4];
  #pragma unroll
  for (int a = 0; a < 4; ++a)
    #pragma unroll
    for (int r = 0; r < 16; ++r) acc[a][r] = 0.f;
  float mrun = -1e30f, lsum = 0.f;

  // ---- prologue: group e stages Kc tile e; all threads stage V tiles 0,1 ----
  {
    const int ts = e;
    gload16(&kv_raw[(bsb + (ts << 5) + krow0) * 4096 + h * 256 + (kunit ^ (krow0 & 15)) * 8],
            &KcB[(ts << 12) + ((s << 3) << 7)]);
    gload16(&kv_raw[(bsb + (ts << 5) + krow0 + 4) * 4096 + h * 256 + (kunit ^ ((krow0 + 4) & 15)) * 8],
            &KcB[(ts << 12) + (((s << 3) + 4) << 7)]);
    int4 v0 = *reinterpret_cast<const int4*>(&kv_raw[(bsb + vkv) * 4096 + h * 256 + 128 + vg * 8]);
    int4 v1 = *reinterpret_cast<const int4*>(&kv_raw[(bsb + 32 + vkv) * 4096 + h * 256 + 128 + vg * 8]);
    const unsigned short* p0 = reinterpret_cast<const unsigned short*>(&v0);
    const unsigned short* p1 = reinterpret_cast<const unsigned short*>(&v1);
    #pragma unroll
    for (int j = 0; j < 8; ++j) VtB[0 * 5120 + (vg * 8 + j) * 40 + vkv] = p0[j];
    #pragma unroll
    for (int j = 0; j < 8; ++j) VtB[1 * 5120 + (vg * 8 + j) * 40 + vkv] = p1[j];
  }
  __syncthreads();

  for (int u = 0; u < U; ++u) {
    {
      int tsK = (u << 1) + 2 + e;
      if (tsK < ntb) {
        int buf = tsK & 3;
        gload16(&kv_raw[(bsb + (tsK << 5) + krow0) * 4096 + h * 256 + (kunit ^ (krow0 & 15)) * 8],
                &KcB[(buf << 12) + ((s << 3) << 7)]);
        gload16(&kv_raw[(bsb + (tsK << 5) + krow0 + 4) * 4096 + h * 256 + (kunit ^ ((krow0 + 4) & 15)) * 8],
                &KcB[(buf << 12) + (((s << 3) + 4) << 7)]);
      }
    }
    int4 vA, vB;
    const int tA = (u << 1) + 2, tB = (u << 1) + 3;
    const bool doA = tA < ntb, doB = tB < ntb;
    if (doA) vA = *reinterpret_cast<const int4*>(
        &kv_raw[(bsb + (tA << 5) + vkv) * 4096 + h * 256 + 128 + vg * 8]);
    if (doB) vB = *reinterpret_cast<const int4*>(
        &kv_raw[(bsb + (tB << 5) + vkv) * 4096 + h * 256 + 128 + vg * 8]);

    const int t = (u << 1) + e;
    if (t < nt_w) {
      const int kvb = t << 5;
      const int kbuf = t & 3;
      short8 krf[4];
      #pragma unroll
      for (int f = 0; f < 4; ++f)
        krf[f] = *reinterpret_cast<const short8*>(
            &krro[(bsb + kvb + l31) * 64 + f * 16 + hi8]);

      f32x16 sca, scb;
      #pragma unroll
      for (int r = 0; r < 16; ++r) { sca[r] = 0.f; scb[r] = 0.f; }
      __builtin_amdgcn_s_setprio(1);
      #pragma unroll
      for (int j = 0; j < 4; ++j) {
        short8 k0 = *reinterpret_cast<const short8*>(
            &KcB[(kbuf << 12) + (l31 << 7) + ((((2 * (2 * j)) | hi) ^ (l31 & 15)) << 3)]);
        sca = __builtin_amdgcn_mfma_f32_32x32x16_bf16(k0, qf[2 * j], sca, 0, 0, 0);
        short8 k1 = *reinterpret_cast<const short8*>(
            &KcB[(kbuf << 12) + (l31 << 7) + ((((2 * (2 * j + 1)) | hi) ^ (l31 & 15)) << 3)]);
        scb = __builtin_amdgcn_mfma_f32_32x32x16_bf16(k1, qf[2 * j + 1], scb, 0, 0, 0);
      }
      sca = __builtin_amdgcn_mfma_f32_32x32x16_bf16(krf[0], qf[8], sca, 0, 0, 0);
      scb = __builtin_amdgcn_mfma_f32_32x32x16_bf16(krf[1], qf[9], scb, 0, 0, 0);
      sca = __builtin_amdgcn_mfma_f32_32x32x16_bf16(krf[2], qf[10], sca, 0, 0, 0);
      scb = __builtin_amdgcn_mfma_f32_32x32x16_bf16(krf[3], qf[11], scb, 0, 0, 0);
      __builtin_amdgcn_s_setprio(0);
      f32x16 sc = sca + scb;

      if (kvb + 31 > q0) {
        #pragma unroll
        for (int r = 0; r < 16; ++r) {
          int kv = kvb + (r & 3) + ((r >> 2) << 3) + (hi << 2);
          if (kv > srow) sc[r] = -1e30f;
        }
      }
      float m0 = fmaxf(fmaxf(sc[0], sc[1]), fmaxf(sc[2], sc[3]));
      float m1 = fmaxf(fmaxf(sc[4], sc[5]), fmaxf(sc[6], sc[7]));
      float m2 = fmaxf(fmaxf(sc[8], sc[9]), fmaxf(sc[10], sc[11]));
      float m3 = fmaxf(fmaxf(sc[12], sc[13]), fmaxf(sc[14], sc[15]));
      float tmax = fmaxf(fmaxf(m0, m1), fmaxf(m2, m3));
      tmax = fmaxf(tmax, __shfl_xor(tmax, 32));

      bool rescale = !__all(tmax <= mrun + 8.f);
      float scold = 1.f;
      if (rescale) {
        float mm = fmaxf(mrun, tmax);
        scold = __expf(mrun - mm);
        mrun = mm;
      }
      float pe[16];
      float ts = 0.f;
      #pragma unroll
      for (int r = 0; r < 16; ++r) { pe[r] = __expf(sc[r] - mrun); ts += pe[r]; }
      ts += __shfl_xor(ts, 32);
      lsum = lsum * scold + ts;

      if (rescale) {
        #pragma unroll
        for (int a = 0; a < 4; ++a)
          #pragma unroll
          for (int r = 0; r < 16; ++r) acc[a][r] *= scold;
      }
      #pragma unroll
      for (int ks = 0; ks < 2; ++ks) {
        unsigned int X0 = cvt_pk_bf16(pe[8 * ks + 0], pe[8 * ks + 1]);
        unsigned int X1 = cvt_pk_bf16(pe[8 * ks + 2], pe[8 * ks + 3]);
        unsigned int Y0 = cvt_pk_bf16(pe[8 * ks + 4], pe[8 * ks + 5]);
        unsigned int Y1 = cvt_pk_bf16(pe[8 * ks + 6], pe[8 * ks + 7]);
        unsigned int send0 = hi ? X0 : Y0;
        unsigned int send1 = hi ? X1 : Y1;
        unsigned int recv0 = (unsigned int)__shfl_xor((int)send0, 32);
        unsigned int recv1 = (unsigned int)__shfl_xor((int)send1, 32);
        union { unsigned int u[4]; short8 v; } pa;
        pa.u[0] = hi ? recv0 : X0;
        pa.u[1] = hi ? recv1 : X1;
        pa.u[2] = hi ? Y0 : recv0;
        pa.u[3] = hi ? Y1 : recv1;
        __builtin_amdgcn_s_setprio(1);
        #pragma unroll
        for (int a = 0; a < 4; ++a) {
          short8 va = *reinterpret_cast<const short8*>(
              &VtB[kbuf * 5120 + (32 * a + l31) * 40 + ks * 16 + hi8]);
          acc[a] = __builtin_amdgcn_mfma_f32_32x32x16_bf16(va, pa.v, acc[a], 0, 0, 0);
        }
        __builtin_amdgcn_s_setprio(0);
      }
    }

    if (doA) {
      const unsigned short* pv = reinterpret_cast<const unsigned short*>(&vA);
      #pragma unroll
      for (int j = 0; j < 8; ++j) VtB[(tA & 3) * 5120 + (vg * 8 + j) * 40 + vkv] = pv[j];
    }
    if (doB) {
      const unsigned short* pv = reinterpret_cast<const unsigned short*>(&vB);
      #pragma unroll
      for (int j = 0; j < 8; ++j) VtB[(tB & 3) * 5120 + (vg * 8 + j) * 40 + vkv] = pv[j];
    }
    __syncthreads();
  }

  // ---- flash merge of parity groups; acc = O^T[v][q=l31], m/l lane-local ----
  if (e == 1) {
    #pragma unroll
    for (int a = 0; a < 4; ++a)
      #pragma unroll
      for (int r = 0; r < 16; ++r) {
        int v = 32 * a + (r & 3) + ((r >> 2) << 3) + (hi << 2);
        Msh[((s << 7) + v) * 33 + l31] = acc[a][r];
      }
    if (hi == 0) {
      Msh[16896 + ((s << 5) + l31) * 2 + 0] = mrun;
      Msh[16896 + ((s << 5) + l31) * 2 + 1] = lsum;
    }
  }
  __syncthreads();
  if (e == 0) {
    float m1 = Msh[16896 + ((s << 5) + l31) * 2 + 0];
    float l1 = Msh[16896 + ((s << 5) + l31) * 2 + 1];
    float mm = fmaxf(mrun, m1);
    float ea = __expf(mrun - mm), eb = __expf(m1 - mm);
    float linv = 1.f / (lsum * ea + l1 * eb);
    float al = ea * linv, be = eb * linv;
    #pragma unroll
    for (int a = 0; a < 4; ++a)
      #pragma unroll
      for (int r = 0; r < 16; ++r) {
        int v = 32 * a + (r & 3) + ((r >> 2) << 3) + (hi << 2);
        float part = Msh[((s << 7) + v) * 33 + l31];
        acc[a][r] = acc[a][r] * al + part * be;
      }
    unsigned int* Tb = reinterpret_cast<unsigned int*>(smem) + s * 4224;
    #pragma unroll
    for (int a = 0; a < 4; ++a)
      #pragma unroll
      for (int j = 0; j < 8; ++j) {
        unsigned int word = cvt_pk_bf16(acc[a][2 * j], acc[a][2 * j + 1]);
        int wc = 16 * a + 2 * hi + (j & 1) + 4 * (j >> 1);
        Tb[l31 * 68 + wc] = word;
      }
    const unsigned char* Tbb = reinterpret_cast<const unsigned char*>(Tb);
    #pragma unroll
    for (int u2 = 0; u2 < 8; ++u2) {
      int qr = (u2 << 2) + (lane >> 4);
      int4 rd = *reinterpret_cast<const int4*>(&Tbb[qr * 272 + (lane & 15) * 16]);
      *reinterpret_cast<int4*>(
          &attn_out[(bsb + q0 + qr) * 2048 + h * 128 + (lane & 15) * 8]) = rd;
    }
  }
}

// ---------------- launch ----------------

extern "C" void kernel_launch(void* const* d_in, const int* in_sizes, int n_in,
                              void* d_out, int out_size, void* d_ws, size_t ws_size,
                              hipStream_t stream) {
  (void)in_sizes; (void)n_in; (void)out_size; (void)ws_size;
  const float* x = (const float*)d_in[0];
  const float* freq = (const float*)d_in[1];
  // d_in[2] = mask: always causal tril -> handled analytically
  const float* w_dq = (const float*)d_in[3];
  const float* b_dq = (const float*)d_in[4];
  const float* w_uq = (const float*)d_in[5];
  const float* b_uq = (const float*)d_in[6];
  const float* w_qr = (const float*)d_in[7];
  const float* b_qr = (const float*)d_in[8];
  const float* w_dkv = (const float*)d_in[9];
  const float* b_dkv = (const float*)d_in[10];
  const float* w_ukv = (const float*)d_in[11];
  const float* b_ukv = (const float*)d_in[12];
  const float* w_kr = (const float*)d_in[13];
  const float* b_kr = (const float*)d_in[14];
  const float* w_o = (const float*)d_in[15];
  const float* b_o = (const float*)d_in[16];

  char* ws = (char*)d_ws;
  size_t off = 0;
  auto alloc = [&](size_t bytes) {
    char* p = ws + off;
    off += (bytes + 255) & ~(size_t)255;
    return p;
  };
  unsigned short* x_bf   = (unsigned short*)alloc((size_t)4096 * 2048 * 2);
  unsigned short* wd_t   = (unsigned short*)alloc((size_t)1344 * 2048 * 2);  // dq|dkv|kr rows
  unsigned short* wqc_t  = (unsigned short*)alloc((size_t)3072 * 768 * 2);
  unsigned short* wukv_t = (unsigned short*)alloc((size_t)4096 * 512 * 2);
  unsigned short* wo_t   = (unsigned short*)alloc((size_t)2048 * 2048 * 2);
  float* tab             = (float*)alloc((size_t)2048 * 32 * 2 * 4);
  float* bcat            = (float*)alloc((size_t)3072 * 4);
  float* ball            = (float*)alloc((size_t)1344 * 4);
  unsigned short* c_all  = (unsigned short*)alloc((size_t)4096 * 1344 * 2);  // c_q|c_kv|kr_raw
  unsigned short* krro   = (unsigned short*)alloc((size_t)4096 * 64 * 2);
  unsigned short* q_raw  = (unsigned short*)alloc((size_t)4096 * 3072 * 2);
  unsigned short* kv_raw = (unsigned short*)alloc((size_t)4096 * 4096 * 2);
  unsigned short* attn   = (unsigned short*)alloc((size_t)4096 * 2048 * 2);

  // single fused prep: 7 transposes + x cast + rope table + bias concat
  k_prep<<<dim3(11250), dim3(256), 0, stream>>>(
      x, freq, w_dq, w_dkv, w_kr, w_uq, w_qr, w_ukv, w_o,
      b_uq, b_qr, b_dq, b_dkv, b_kr,
      x_bf, wd_t, wqc_t, wukv_t, wo_t, tab, bcat, ball);

  // single merged down-projection: x @ [w_dq|w_dkv|w_kr] -> c_all [4096][1344]
  k_gemm_bt<1><<<dim3(11, 32), dim3(256), 0, stream>>>(
      x_bf, wd_t, ball, c_all, 4096, 1344, 2048, 2048, 1344);
  k_rope_kr<<<dim3(512), dim3(256), 0, stream>>>(c_all + 1280, 1344, tab, krro, 4096 * 32);

  // up-projections
  k_gemm_bt<1><<<dim3(24, 32), dim3(256), 0, stream>>>(
      c_all, wqc_t, bcat, q_raw, 4096, 3072, 768, 1344, 3072);
  k_gemm_bt<1><<<dim3(32, 32), dim3(256), 0, stream>>>(
      c_all + 768, wukv_t, b_ukv, kv_raw, 4096, 4096, 512, 1344, 4096);

  // fused causal attention: 512 blocks, one chunk each, 2 blocks/CU co-resident
  k_mla_attn<<<dim3(512), dim3(512), 0, stream>>>(q_raw, kv_raw, krro, tab, attn);

  // output projection -> f32
  k_gemm_bt<0><<<dim3(16, 32), dim3(256), 0, stream>>>(
      attn, wo_t, b_o, (float*)d_out, 4096, 2048, 2048, 2048, 2048);
}